// Round 5
// baseline (38.653 us; speedup 1.0000x reference)
//
#include <hip/hip_runtime.h>
#include <hip/hip_bf16.h>

#define N 1024
#define D 64

typedef __attribute__((ext_vector_type(8))) short bf16x8;
typedef __attribute__((ext_vector_type(16))) float f32x16;
typedef __attribute__((ext_vector_type(2))) float f32x2;

__device__ __forceinline__ unsigned short f2bf(float x) {
    __hip_bfloat16 b = __float2bfloat16(x);
    return (unsigned short)__builtin_bit_cast(short, b);
}

// h1 = relu(hi + hjb) on a packed bf16x2 pair; f32 pk math, repack to bf16x2.
__device__ __forceinline__ unsigned h1p(unsigned a, unsigned b) {
    f32x2 av, bv;
    av.x = __builtin_bit_cast(float, a << 16);
    av.y = __builtin_bit_cast(float, a & 0xffff0000u);
    bv.x = __builtin_bit_cast(float, b << 16);
    bv.y = __builtin_bit_cast(float, b & 0xffff0000u);
    f32x2 s = av + bv;
    f32x2 z = {0.0f, 0.0f};
    s = __builtin_elementwise_max(s, z);
    return (unsigned)f2bf(s.x) | ((unsigned)f2bf(s.y) << 16);
}

// ---------------------------------------------------------------------------
// K1: hih = pack_bf16(X@w1a^T) ; hjbh = pack_bf16(X@w1b^T + b1) ;
//     trfb = bf16(X@sig_w^T + sb).   grid 256, block 256.
// ---------------------------------------------------------------------------
__global__ __launch_bounds__(256) void precompute_kernel(
    const float* __restrict__ cell, const float* __restrict__ w1,
    const float* __restrict__ b1, const float* __restrict__ sw,
    const float* __restrict__ sb,
    unsigned* __restrict__ hih, unsigned* __restrict__ hjbh,
    unsigned short* __restrict__ trfb)
{
    __shared__ float w1s[64 * 129];
    __shared__ float sws[64 * 65];
    __shared__ float xs[4 * 64];
    const int t = threadIdx.x;
    const int b = blockIdx.x;
    #pragma unroll
    for (int k = 0; k < 8; k++) {
        int f4 = t + 256 * k;
        int row = f4 >> 5, c4 = (f4 & 31) * 4;
        float4 v = *(const float4*)&w1[(size_t)row * 128 + c4];
        w1s[row * 129 + c4 + 0] = v.x;
        w1s[row * 129 + c4 + 1] = v.y;
        w1s[row * 129 + c4 + 2] = v.z;
        w1s[row * 129 + c4 + 3] = v.w;
    }
    #pragma unroll
    for (int k = 0; k < 4; k++) {
        int f4 = t + 256 * k;
        int row = f4 >> 4, c4 = (f4 & 15) * 4;
        float4 v = *(const float4*)&sw[(size_t)row * 64 + c4];
        sws[row * 65 + c4 + 0] = v.x;
        sws[row * 65 + c4 + 1] = v.y;
        sws[row * 65 + c4 + 2] = v.z;
        sws[row * 65 + c4 + 3] = v.w;
    }
    xs[t] = cell[(size_t)b * 256 + t];
    __syncthreads();
    const int wv = t >> 6, l = t & 63;
    const float* xr = &xs[wv * 64];
    float a0 = 0.0f, a1 = 0.0f, a2 = 0.0f;
    #pragma unroll 16
    for (int d = 0; d < 64; d++) {
        float x = xr[d];
        a0 = fmaf(x, w1s[l * 129 + d], a0);
        a1 = fmaf(x, w1s[l * 129 + 64 + d], a1);
        a2 = fmaf(x, sws[l * 65 + d], a2);
    }
    const int i = b * 4 + wv;
    unsigned s0 = f2bf(a0);
    unsigned s1 = f2bf(a1 + b1[l]);
    unsigned p0 = (unsigned)__shfl_xor((int)s0, 1);
    unsigned p1 = (unsigned)__shfl_xor((int)s1, 1);
    if (!(l & 1)) {
        hih [i * 32 + (l >> 1)] = s0 | (p0 << 16);
        hjbh[i * 32 + (l >> 1)] = s1 | (p1 << 16);
    }
    trfb[i * 64 + l] = f2bf(a2 + sb[l]);
}

// ---------------------------------------------------------------------------
// K2: fused pairwise gate MLP + unnormalized weighted accumulation.
// i-tile 32, j-tile 32, 4 waves (8 j each); wave-pairs share one 16-k
// out-MFMA group (unused wf slots zero; LDS reduce sums). grid (32,32).
// ---------------------------------------------------------------------------
__global__ __launch_bounds__(256, 4) void gate_fused_kernel(
    const float* __restrict__ A, const unsigned* __restrict__ hih,
    const unsigned* __restrict__ hjbh, const unsigned short* __restrict__ trfb,
    const float* __restrict__ w2, const float* __restrict__ b2,
    const float* __restrict__ w3, const float* __restrict__ b3,
    float* __restrict__ part, float* __restrict__ rsp)
{
    __shared__ float smem[8320];
    unsigned* hjbh_s = (unsigned*)smem;        // [32 j][32 k2]  (4 KB)
    float*    S1     = smem + 1024;            // [32 j][32 i]   (4 KB)
    float*    T2t    = smem + 2048;            // [32 j][33 i]   (4.2 KB)
    const int t   = threadIdx.x;
    const int w   = t >> 6;
    const int l   = t & 63;
    const int i0  = blockIdx.x * 32;
    const int by  = blockIdx.y;
    const int jb0 = by * 32;
    const int p   = l & 31;
    const int hi8 = l >> 5;
    const int i_mine = i0 + p;

    // ---- stage: hjbh rows, A[j][i-tile], A[i-tile][j] transposed ----
    {
        int row = t >> 3, c4 = (t & 7) * 4;
        *(uint4*)&hjbh_s[row * 32 + c4] =
            *(const uint4*)&hjbh[(size_t)(jb0 + row) * 32 + c4];
        *(float4*)&S1[row * 32 + c4] =
            *(const float4*)&A[(size_t)(jb0 + row) * N + i0 + c4];
        float4 v = *(const float4*)&A[(size_t)(i0 + row) * N + jb0 + c4];
        T2t[(c4 + 0) * 33 + row] = v.x;
        T2t[(c4 + 1) * 33 + row] = v.y;
        T2t[(c4 + 2) * 33 + row] = v.z;
        T2t[(c4 + 3) * 33 + row] = v.w;
    }

    // ---- loop-invariant operands ----
    uint4 hvb[4];
    #pragma unroll
    for (int q = 0; q < 4; q++)
        hvb[q] = *(const uint4*)&hih[(size_t)i_mine * 32 + q * 8 + hi8 * 4];

    bf16x8 wa[4];
    #pragma unroll
    for (int q = 0; q < 4; q++) {
        float4 v0 = *(const float4*)&w2[(size_t)p * D + q * 16 + hi8 * 8];
        float4 v1 = *(const float4*)&w2[(size_t)p * D + q * 16 + hi8 * 8 + 4];
        wa[q][0] = (short)f2bf(v0.x); wa[q][1] = (short)f2bf(v0.y);
        wa[q][2] = (short)f2bf(v0.z); wa[q][3] = (short)f2bf(v0.w);
        wa[q][4] = (short)f2bf(v1.x); wa[q][5] = (short)f2bf(v1.y);
        wa[q][6] = (short)f2bf(v1.z); wa[q][7] = (short)f2bf(v1.w);
    }
    f32x2 b2v[8], w3v[8];
    #pragma unroll
    for (int g = 0; g < 4; g++) {
        float4 qb = *(const float4*)&b2[g * 8 + hi8 * 4];
        float4 qw = *(const float4*)&w3[g * 8 + hi8 * 4];
        b2v[2 * g].x = qb.x;     b2v[2 * g].y = qb.y;
        b2v[2 * g + 1].x = qb.z; b2v[2 * g + 1].y = qb.w;
        w3v[2 * g].x = qw.x;     w3v[2 * g].y = qw.y;
        w3v[2 * g + 1].x = qw.z; w3v[2 * g + 1].y = qw.w;
    }
    const float b3v = b3[0];
    const bool wsel = ((w & 1) == hi8);   // this wave's wf slots live in this half

    __syncthreads();

    bf16x8 wf = {0, 0, 0, 0, 0, 0, 0, 0};
    float es = 0.0f;
    #pragma unroll
    for (int jj = 0; jj < 8; jj++) {
        const int jl = w * 8 + jj;
        const int j  = jb0 + jl;

        f32x16 accA, accB;
        #pragma unroll
        for (int r2 = 0; r2 < 8; r2++) {
            accA[2 * r2] = b2v[r2].x; accA[2 * r2 + 1] = b2v[r2].y;
            accB[2 * r2] = 0.0f;      accB[2 * r2 + 1] = 0.0f;
        }
        #pragma unroll
        for (int q = 0; q < 4; q++) {
            uint4 hb4 = *(const uint4*)&hjbh_s[jl * 32 + q * 8 + hi8 * 4];
            uint4 fr;
            fr.x = h1p(hvb[q].x, hb4.x);
            fr.y = h1p(hvb[q].y, hb4.y);
            fr.z = h1p(hvb[q].z, hb4.z);
            fr.w = h1p(hvb[q].w, hb4.w);
            bf16x8 frag = __builtin_bit_cast(bf16x8, fr);
            if (q < 2)
                accA = __builtin_amdgcn_mfma_f32_32x32x16_bf16(wa[q], frag, accA, 0, 0, 0);
            else
                accB = __builtin_amdgcn_mfma_f32_32x32x16_bf16(wa[q], frag, accB, 0, 0, 0);
        }

        // gate_pre: two independent pk-fma chains, then horizontal
        f32x2 g0 = {0.0f, 0.0f}, g1 = {0.0f, 0.0f};
        f32x2 z2 = {0.0f, 0.0f};
        #pragma unroll
        for (int r2 = 0; r2 < 8; r2++) {
            f32x2 s;
            s.x = accA[2 * r2] + accB[2 * r2];
            s.y = accA[2 * r2 + 1] + accB[2 * r2 + 1];
            s = __builtin_elementwise_max(s, z2);
            if (r2 & 1) g1 = __builtin_elementwise_fma(s, w3v[r2], g1);
            else        g0 = __builtin_elementwise_fma(s, w3v[r2], g0);
        }
        g0 += g1;
        float gp = g0.x + g0.y;
        gp += __shfl_xor(gp, 32);

        const bool isdiag = (i_mine == j);
        float sym  = 0.5f * (S1[jl * 32 + p] + T2t[jl * 33 + p]);
        float e    = isdiag ? 1.0f : __expf(sym);
        float gate = 1.0f / (1.0f + __expf(-(gp + b3v)));
        float u    = isdiag ? 0.0f : gate * e;
        if ((jj >> 2) == hi8) es += e;
        short ub = (short)f2bf(u);
        wf[jj] = wsel ? ub : wf[jj];
    }
    es += __shfl_xor(es, 32);

    // ---- out tile: U(32i x 16j-group) @ trf(16j x 64d), wave-pair shared ----
    const int grp = w >> 1;
    bf16x8 tf0, tf1;
    #pragma unroll
    for (int e8 = 0; e8 < 8; e8++) {
        const unsigned short* tp =
            &trfb[(size_t)(jb0 + grp * 16 + hi8 * 8 + e8) * 64];
        tf0[e8] = (short)tp[p];
        tf1[e8] = (short)tp[32 + p];
    }
    f32x16 oA, oB;
    #pragma unroll
    for (int r = 0; r < 16; r++) { oA[r] = 0.0f; oB[r] = 0.0f; }
    oA = __builtin_amdgcn_mfma_f32_32x32x16_bf16(wf, tf0, oA, 0, 0, 0);
    oB = __builtin_amdgcn_mfma_f32_32x32x16_bf16(wf, tf1, oB, 0, 0, 0);

    __syncthreads();   // staged LDS no longer needed
    float* red = smem;           // 4 x 2048
    float* esb = smem + 8192;    // 128
    #pragma unroll
    for (int r = 0; r < 16; r++) {
        int row = (r & 3) + 8 * (r >> 2) + 4 * hi8;
        red[w * 2048 + row * 64 + p]      = oA[r];
        red[w * 2048 + row * 64 + 32 + p] = oB[r];
    }
    if (hi8 == 0) esb[w * 32 + p] = es;
    __syncthreads();
    #pragma unroll
    for (int e = 0; e < 8; e++) {
        int idx = t + e * 256;
        float s = red[idx] + red[2048 + idx] + red[4096 + idx] + red[6144 + idx];
        part[(size_t)by * (N * D) + (size_t)i0 * D + idx] = s;
    }
    if (t < 32)
        rsp[by * N + i0 + t] = esb[t] + esb[32 + t] + esb[64 + t] + esb[96 + t];
}

// ---------------------------------------------------------------------------
// K3: out = cell + (sum_by part) / (sum_by rsp). grid 256, block 256.
// ---------------------------------------------------------------------------
__global__ __launch_bounds__(256) void finish_kernel(
    const float* __restrict__ cell, const float* __restrict__ part,
    const float* __restrict__ rsp, float* __restrict__ out)
{
    const int idx = blockIdx.x * 256 + threadIdx.x;
    const int i = idx >> 6;
    float rs = 0.0f;
    #pragma unroll
    for (int k = 0; k < 32; k++) rs += rsp[k * N + i];
    float acc = 0.0f;
    #pragma unroll
    for (int k = 0; k < 32; k++) acc += part[(size_t)k * (N * D) + idx];
    out[idx] = cell[idx] + acc / rs;
}

// ---------------------------------------------------------------------------
extern "C" void kernel_launch(void* const* d_in, const int* in_sizes, int n_in,
                              void* d_out, int out_size, void* d_ws, size_t ws_size,
                              hipStream_t stream) {
    const float* cell = (const float*)d_in[0];
    const float* adj  = (const float*)d_in[1];
    const float* w1   = (const float*)d_in[2];
    const float* b1   = (const float*)d_in[3];
    const float* w2   = (const float*)d_in[4];
    const float* b2   = (const float*)d_in[5];
    const float* w3   = (const float*)d_in[6];
    const float* b3   = (const float*)d_in[7];
    const float* sw   = (const float*)d_in[8];
    const float* sb   = (const float*)d_in[9];
    float* out = (float*)d_out;

    unsigned*       hih  = (unsigned*)d_ws;            // 32768 u32
    unsigned*       hjbh = hih + N * 32;               // 32768 u32
    unsigned short* trfb = (unsigned short*)(hjbh + N * 32); // 65536 u16
    float*          part = (float*)(trfb + N * 64);    // 32 x 64K f32
    float*          rsp  = part + (size_t)32 * N * D;  // 32 x 1024 f32

    precompute_kernel<<<256, 256, 0, stream>>>(cell, w1, b1, sw, sb,
                                               hih, hjbh, trfb);
    gate_fused_kernel<<<dim3(32, 32), 256, 0, stream>>>(adj, hih, hjbh, trfb,
                                                        w2, b2, w3, b3,
                                                        part, rsp);
    finish_kernel<<<256, 256, 0, stream>>>(cell, part, rsp, out);
}